// Round 1
// baseline (96.322 us; speedup 1.0000x reference)
//
#include <hip/hip_runtime.h>

#define D 512
#define C 256
#define B 512
#define NS 8192

// ---------------- reduction helpers (256-thread block) ----------------
__device__ __forceinline__ float block_reduce_sum(float v, float* sm) {
    int tid = threadIdx.x;
    sm[tid] = v;
    __syncthreads();
    for (int s = 128; s > 0; s >>= 1) {
        if (tid < s) sm[tid] += sm[tid + s];
        __syncthreads();
    }
    float r = sm[0];
    __syncthreads();
    return r;
}

__device__ __forceinline__ float block_reduce_max(float v, float* sm) {
    int tid = threadIdx.x;
    sm[tid] = v;
    __syncthreads();
    for (int s = 128; s > 0; s >>= 1) {
        if (tid < s) sm[tid] = fmaxf(sm[tid], sm[tid + s]);
        __syncthreads();
    }
    float r = sm[0];
    __syncthreads();
    return r;
}

// ---------------- segment sum: sums[y[i]] += x[i], counts[y[i]] += 1 ----------------
__global__ void seg_sum_kernel(const float* __restrict__ x, const int* __restrict__ y,
                               float* __restrict__ sums, float* __restrict__ counts) {
    int i = blockIdx.x;
    int cls = y[i];
    const float* xr = x + (size_t)i * D;
    float* sr = sums + (size_t)cls * D;
    int tid = threadIdx.x;
    atomicAdd(&sr[tid], xr[tid]);
    atomicAdd(&sr[tid + 256], xr[tid + 256]);
    if (tid == 0) atomicAdd(&counts[cls], 1.0f);
}

// ---------------- nm[c] = ||mus[c]||^2 ----------------
__global__ void nm_kernel(const float* __restrict__ mus, float* __restrict__ nm) {
    __shared__ float sm[256];
    int c = blockIdx.x, tid = threadIdx.x;
    float v0 = mus[(size_t)c * D + tid];
    float v1 = mus[(size_t)c * D + tid + 256];
    float s = block_reduce_sum(v0 * v0 + v1 * v1, sm);
    if (tid == 0) nm[c] = s;
}

// ---------------- intra-class variance numerators: d2sum[yq[i]] += ||xq[i]-mean||^2 ----------------
__global__ void var_kernel(const float* __restrict__ xq, const int* __restrict__ yq,
                           const float* __restrict__ qsum, const float* __restrict__ qcount,
                           float* __restrict__ d2sum) {
    __shared__ float sm[256];
    int i = blockIdx.x, tid = threadIdx.x;
    int cls = yq[i];
    float denom = fmaxf(qcount[cls], 1.0f);
    float s = 0.f;
#pragma unroll
    for (int k = 0; k < 2; ++k) {
        int d = tid + k * 256;
        float diff = xq[(size_t)i * D + d] - qsum[(size_t)cls * D + d] / denom;
        s += diff * diff;
    }
    s = block_reduce_sum(s, sm);
    if (tid == 0) atomicAdd(&d2sum[cls], s);
}

// ---------------- G[b,c] = xq[b] . mus[c]   (8 query rows per block) ----------------
__global__ void gemm_kernel(const float* __restrict__ xq, const float* __restrict__ mus,
                            float* __restrict__ G) {
    __shared__ __align__(16) float xqs[8][D];
    int tid = threadIdx.x;
    int b0 = blockIdx.x * 8;
    for (int k = tid; k < 8 * D; k += 256) {
        xqs[k >> 9][k & (D - 1)] = xq[(size_t)b0 * D + k];
    }
    __syncthreads();
    const float4* mrow = (const float4*)(mus + (size_t)tid * D);
    float acc[8] = {0.f, 0.f, 0.f, 0.f, 0.f, 0.f, 0.f, 0.f};
    for (int d4 = 0; d4 < D / 4; ++d4) {
        float4 m = mrow[d4];
#pragma unroll
        for (int r = 0; r < 8; ++r) {
            const float4 xv = *(const float4*)&xqs[r][d4 * 4];
            acc[r] += m.x * xv.x + m.y * xv.y + m.z * xv.z + m.w * xv.w;
        }
    }
    for (int r = 0; r < 8; ++r)
        G[(size_t)(b0 + r) * C + tid] = acc[r];
}

// ---------------- per-query logits + log-softmax + loss accumulation ----------------
__global__ void loss_kernel(const float* __restrict__ xq, const int* __restrict__ ys,
                            const int* __restrict__ pos, const float* __restrict__ G,
                            const float* __restrict__ nm, const float* __restrict__ cc,
                            float* __restrict__ loss_acc) {
    __shared__ float sm[256];
    __shared__ float sh_t;
    int b = blockIdx.x, tid = threadIdx.x;
    int t = ys[pos[b]];
    float v0 = xq[(size_t)b * D + tid];
    float v1 = xq[(size_t)b * D + tid + 256];
    float nq = block_reduce_sum(v0 * v0 + v1 * v1, sm);

    int c = tid;  // 256 threads == 256 classes
    float count = cc[c];
    float g = G[(size_t)b * C + c];
    float Cn, dot, m2;
    if (c == t) {
        Cn = count - 1.0f;
        dot = g - nq;
        m2 = nm[c] - 2.0f * g + nq;
    } else {
        Cn = count;
        dot = g;
        m2 = nm[c];
    }
    float den = fmaxf(Cn, 0.1f);
    float inv = 1.0f / den;
    float dist2 = nq - 2.0f * dot * inv + m2 * inv * inv;
    float logit = (Cn > 0.1f) ? (-0.5f * dist2) : 0.0f;
    if (c == t) sh_t = logit;  // read after reductions' syncthreads

    float mx = block_reduce_max(logit, sm);
    float e = expf(logit - mx);
    float se = block_reduce_sum(e, sm);
    if (tid == 0) {
        float logp_t = sh_t - mx - logf(se);
        atomicAdd(loss_acc, -logp_t / (float)B);
    }
}

// ---------------- finalize: var_intra + write outputs ----------------
__global__ void final_kernel(const float* __restrict__ qcount, const float* __restrict__ d2sum,
                             const float* __restrict__ loss_acc, float* __restrict__ out) {
    __shared__ float sm[256];
    int c = threadIdx.x;
    float cnt = qcount[c];
    bool valid = cnt >= 3.0f;  // MIN_SAMPLES
    float tot = block_reduce_sum(valid ? d2sum[c] : 0.0f, sm);  // var_c*count == d2sum
    float cnt_total = block_reduce_sum(valid ? cnt : 0.0f, sm);
    if (c == 0) {
        out[0] = loss_acc[0];
        out[1] = (cnt_total > 0.f) ? tot / fmaxf(cnt_total, 1.0f) : 0.0f;
    }
}

extern "C" void kernel_launch(void* const* d_in, const int* in_sizes, int n_in,
                              void* d_out, int out_size, void* d_ws, size_t ws_size,
                              hipStream_t stream) {
    const float* xq = (const float*)d_in[0];
    const int* yq = (const int*)d_in[1];
    const float* xs = (const float*)d_in[2];
    const int* ys = (const int*)d_in[3];
    const int* pos = (const int*)d_in[4];
    float* out = (float*)d_out;

    float* ws = (float*)d_ws;
    float* mus = ws;                     // 131072  (C*D)  [zeroed]
    float* qsum = ws + 131072;           // 131072  (C*D)  [zeroed]
    float* class_count = ws + 262144;    // 256            [zeroed]
    float* qcount = ws + 262400;         // 256            [zeroed]
    float* d2sum = ws + 262656;          // 256            [zeroed]
    float* loss_acc = ws + 262912;       // 1              [zeroed]
    float* nm = ws + 263168;             // 256
    float* G = ws + 263424;              // 131072 (B*C)   -> total 394496 floats

    hipMemsetAsync(d_ws, 0, (size_t)262913 * sizeof(float), stream);

    seg_sum_kernel<<<NS, 256, 0, stream>>>(xs, ys, mus, class_count);
    seg_sum_kernel<<<B, 256, 0, stream>>>(xq, yq, qsum, qcount);
    nm_kernel<<<C, 256, 0, stream>>>(mus, nm);
    var_kernel<<<B, 256, 0, stream>>>(xq, yq, qsum, qcount, d2sum);
    gemm_kernel<<<B / 8, 256, 0, stream>>>(xq, mus, G);
    loss_kernel<<<B, 256, 0, stream>>>(xq, ys, pos, G, nm, class_count, loss_acc);
    final_kernel<<<1, 256, 0, stream>>>(qcount, d2sum, loss_acc, out);
}

// Round 2
// 47.339 us; speedup vs baseline: 2.0347x; 2.0347x over previous
//
#include <hip/hip_runtime.h>

#define D 512
#define C 256
#define B 512
#define NS 8192

template <int NT>
__device__ __forceinline__ float block_reduce_sum(float v, float* sm) {
    int tid = threadIdx.x;
    sm[tid] = v;
    __syncthreads();
    for (int s = NT / 2; s > 0; s >>= 1) {
        if (tid < s) sm[tid] += sm[tid + s];
        __syncthreads();
    }
    float r = sm[0];
    __syncthreads();
    return r;
}

template <int NT>
__device__ __forceinline__ float block_reduce_max(float v, float* sm) {
    int tid = threadIdx.x;
    sm[tid] = v;
    __syncthreads();
    for (int s = NT / 2; s > 0; s >>= 1) {
        if (tid < s) sm[tid] = fmaxf(sm[tid], sm[tid + s]);
        __syncthreads();
    }
    float r = sm[0];
    __syncthreads();
    return r;
}

// ---- per-class prototype sum + count + ||mus||^2 (no atomics, no pre-zero) ----
// one block per class, 512 threads (thread = dim)
__global__ void proto_kernel(const float* __restrict__ xs, const int* __restrict__ ys,
                             float* __restrict__ mus, float* __restrict__ counts,
                             float* __restrict__ nm) {
    __shared__ int list[NS];  // 32 KB
    __shared__ int cnt;
    __shared__ float sm[512];
    int c = blockIdx.x, tid = threadIdx.x;
    if (tid == 0) cnt = 0;
    __syncthreads();
    for (int i = tid; i < NS; i += 512)
        if (ys[i] == c) { int p = atomicAdd(&cnt, 1); list[p] = i; }
    __syncthreads();
    int n = cnt;
    float a0 = 0.f, a1 = 0.f, a2 = 0.f, a3 = 0.f;
    int j = 0;
    for (; j + 4 <= n; j += 4) {
        a0 += xs[(size_t)list[j + 0] * D + tid];
        a1 += xs[(size_t)list[j + 1] * D + tid];
        a2 += xs[(size_t)list[j + 2] * D + tid];
        a3 += xs[(size_t)list[j + 3] * D + tid];
    }
    for (; j < n; ++j) a0 += xs[(size_t)list[j] * D + tid];
    float m = (a0 + a1) + (a2 + a3);
    mus[(size_t)c * D + tid] = m;
    float s = block_reduce_sum<512>(m * m, sm);
    if (tid == 0) { nm[c] = s; counts[c] = (float)n; }
}

// ---- per-class query stats: count + intra-class d2 numerator (closed form) ----
// d2sum[c] = sum_i ||xq_i||^2 - ||sum_i xq_i||^2 / n   for samples of class c
__global__ void qstats_kernel(const float* __restrict__ xq, const int* __restrict__ yq,
                              float* __restrict__ qcount, float* __restrict__ d2sum) {
    __shared__ int list[B];
    __shared__ int cnt;
    __shared__ float sm[512];
    int c = blockIdx.x, tid = threadIdx.x;
    if (tid == 0) cnt = 0;
    __syncthreads();
    if (yq[tid] == c) { int p = atomicAdd(&cnt, 1); list[p] = tid; }  // blockDim == B == 512
    __syncthreads();
    int n = cnt;
    float s = 0.f, sq = 0.f;
    for (int j = 0; j < n; ++j) {
        float v = xq[(size_t)list[j] * D + tid];
        s += v;
        sq += v * v;
    }
    float nrm = block_reduce_sum<512>(s * s, sm);
    float tsq = block_reduce_sum<512>(sq, sm);
    if (tid == 0) {
        qcount[c] = (float)n;
        d2sum[c] = (n > 0) ? (tsq - nrm / (float)n) : 0.f;
    }
}

// ---- fused GEMM (xq . mus^T) + leave-one-out logits + log-softmax + per-row loss ----
// 256 threads (thread = class), ROWS query rows per block
#define ROWS 4
__global__ void gemm_loss_kernel(const float* __restrict__ xq, const int* __restrict__ ys,
                                 const int* __restrict__ pos, const float* __restrict__ mus,
                                 const float* __restrict__ nm, const float* __restrict__ cc,
                                 float* __restrict__ loss_b) {
    __shared__ __align__(16) float xqs[ROWS][D];
    __shared__ float sm[256];
    __shared__ float sh_t;
    int tid = threadIdx.x;
    int b0 = blockIdx.x * ROWS;
    for (int k = tid; k < ROWS * D; k += 256)
        xqs[k >> 9][k & (D - 1)] = xq[(size_t)b0 * D + k];
    __syncthreads();

    float nqv[ROWS];
#pragma unroll
    for (int r = 0; r < ROWS; ++r) {
        float v0 = xqs[r][tid], v1 = xqs[r][tid + 256];
        nqv[r] = block_reduce_sum<256>(v0 * v0 + v1 * v1, sm);
    }

    const float4* mrow = (const float4*)(mus + (size_t)tid * D);
    float acc[ROWS] = {0.f, 0.f, 0.f, 0.f};
    for (int d4 = 0; d4 < D / 4; ++d4) {
        float4 m = mrow[d4];
#pragma unroll
        for (int r = 0; r < ROWS; ++r) {
            const float4 xv = *(const float4*)&xqs[r][d4 * 4];
            acc[r] += m.x * xv.x + m.y * xv.y + m.z * xv.z + m.w * xv.w;
        }
    }

    float count = cc[tid];
    float nmv = nm[tid];
#pragma unroll
    for (int r = 0; r < ROWS; ++r) {
        int b = b0 + r;
        int t = ys[pos[b]];
        float nq = nqv[r];
        float g = acc[r];
        float Cn, dot, m2;
        if (tid == t) {
            Cn = count - 1.0f; dot = g - nq; m2 = nmv - 2.0f * g + nq;
        } else {
            Cn = count; dot = g; m2 = nmv;
        }
        float den = fmaxf(Cn, 0.1f);
        float inv = 1.0f / den;
        float dist2 = nq - 2.0f * dot * inv + m2 * inv * inv;
        float logit = (Cn > 0.1f) ? (-0.5f * dist2) : 0.0f;
        if (tid == t) sh_t = logit;
        float mx = block_reduce_max<256>(logit, sm);
        float e = expf(logit - mx);
        float se = block_reduce_sum<256>(e, sm);
        if (tid == 0) loss_b[b] = -(sh_t - mx - logf(se));
        __syncthreads();  // protect sh_t before next row overwrites it
    }
}

// ---- finalize: mean loss + intra-class variance ----
__global__ void final_kernel(const float* __restrict__ qcount, const float* __restrict__ d2sum,
                             const float* __restrict__ loss_b, float* __restrict__ out) {
    __shared__ float sm[256];
    int tid = threadIdx.x;
    float cnt = qcount[tid];
    bool valid = cnt >= 3.0f;  // MIN_SAMPLES
    float tot = block_reduce_sum<256>(valid ? d2sum[tid] : 0.0f, sm);
    float ctot = block_reduce_sum<256>(valid ? cnt : 0.0f, sm);
    float lsum = block_reduce_sum<256>(loss_b[tid] + loss_b[tid + 256], sm);
    if (tid == 0) {
        out[0] = lsum / (float)B;
        out[1] = (ctot > 0.f) ? tot / fmaxf(ctot, 1.0f) : 0.0f;
    }
}

extern "C" void kernel_launch(void* const* d_in, const int* in_sizes, int n_in,
                              void* d_out, int out_size, void* d_ws, size_t ws_size,
                              hipStream_t stream) {
    const float* xq = (const float*)d_in[0];
    const int* yq = (const int*)d_in[1];
    const float* xs = (const float*)d_in[2];
    const int* ys = (const int*)d_in[3];
    const int* pos = (const int*)d_in[4];
    float* out = (float*)d_out;

    float* ws = (float*)d_ws;
    float* mus = ws;                   // C*D = 131072
    float* counts = ws + 131072;       // 256
    float* nm = ws + 131328;           // 256
    float* qcount = ws + 131584;       // 256
    float* d2sum = ws + 131840;        // 256
    float* loss_b = ws + 132096;       // 512
    // every slot fully written each launch -> no zero-init, no memset

    proto_kernel<<<C, 512, 0, stream>>>(xs, ys, mus, counts, nm);
    qstats_kernel<<<C, 512, 0, stream>>>(xq, yq, qcount, d2sum);
    gemm_loss_kernel<<<B / ROWS, 256, 0, stream>>>(xq, ys, pos, mus, nm, counts, loss_b);
    final_kernel<<<1, 256, 0, stream>>>(qcount, d2sum, loss_b, out);
}

// Round 3
// 44.339 us; speedup vs baseline: 2.1724x; 1.0677x over previous
//
#include <hip/hip_runtime.h>

#define D 512
#define C 256
#define B 512
#define NS 8192

__device__ __forceinline__ float wave_sum(float v) {
#pragma unroll
    for (int off = 32; off > 0; off >>= 1) v += __shfl_xor(v, off, 64);
    return v;
}
__device__ __forceinline__ float wave_max(float v) {
#pragma unroll
    for (int off = 32; off > 0; off >>= 1) v = fmaxf(v, __shfl_xor(v, off, 64));
    return v;
}
// NW = number of 64-lane waves in the block; 2 barriers total
template <int NW>
__device__ __forceinline__ float block_sum(float v, float* sm) {
    v = wave_sum(v);
    int tid = threadIdx.x;
    if ((tid & 63) == 0) sm[tid >> 6] = v;
    __syncthreads();
    float r = 0.f;
#pragma unroll
    for (int w = 0; w < NW; ++w) r += sm[w];
    __syncthreads();
    return r;
}
template <int NW>
__device__ __forceinline__ float block_max(float v, float* sm) {
    v = wave_max(v);
    int tid = threadIdx.x;
    if ((tid & 63) == 0) sm[tid >> 6] = v;
    __syncthreads();
    float r = sm[0];
#pragma unroll
    for (int w = 1; w < NW; ++w) r = fmaxf(r, sm[w]);
    __syncthreads();
    return r;
}

// ---- K1: blocks [0,C) = class prototypes from xs; blocks [C,2C) = query stats + row norms ----
// 512 threads (thread = dim)
__global__ void stats_kernel(const float* __restrict__ xq, const int* __restrict__ yq,
                             const float* __restrict__ xs, const int* __restrict__ ys,
                             float* __restrict__ mus, float* __restrict__ counts,
                             float* __restrict__ nm, float* __restrict__ qcount,
                             float* __restrict__ d2sum, float* __restrict__ nq,
                             float* __restrict__ out) {
    __shared__ int list[NS];  // 32 KB (proto uses NS, qstats uses first B)
    __shared__ int cnt;
    __shared__ float sm[8];
    int bid = blockIdx.x, tid = threadIdx.x;

    if (bid < C) {
        int c = bid;
        if (tid == 0) cnt = 0;
        __syncthreads();
        for (int i = tid; i < NS; i += 512)
            if (ys[i] == c) { int p = atomicAdd(&cnt, 1); list[p] = i; }
        __syncthreads();
        int n = cnt;
        float a0 = 0.f, a1 = 0.f, a2 = 0.f, a3 = 0.f, a4 = 0.f, a5 = 0.f, a6 = 0.f, a7 = 0.f;
        int j = 0;
        for (; j + 8 <= n; j += 8) {
            a0 += xs[(size_t)list[j + 0] * D + tid];
            a1 += xs[(size_t)list[j + 1] * D + tid];
            a2 += xs[(size_t)list[j + 2] * D + tid];
            a3 += xs[(size_t)list[j + 3] * D + tid];
            a4 += xs[(size_t)list[j + 4] * D + tid];
            a5 += xs[(size_t)list[j + 5] * D + tid];
            a6 += xs[(size_t)list[j + 6] * D + tid];
            a7 += xs[(size_t)list[j + 7] * D + tid];
        }
        for (; j < n; ++j) a0 += xs[(size_t)list[j] * D + tid];
        float m = ((a0 + a1) + (a2 + a3)) + ((a4 + a5) + (a6 + a7));
        mus[(size_t)c * D + tid] = m;
        float s = block_sum<8>(m * m, sm);
        if (tid == 0) { nm[c] = s; counts[c] = (float)n; }
    } else {
        int c = bid - C;
        if (tid == 0) cnt = 0;
        __syncthreads();
        if (yq[tid] == c) { int p = atomicAdd(&cnt, 1); list[p] = tid; }  // blockDim == B
        __syncthreads();
        int n = cnt;
        float ssum = 0.f, tsq = 0.f;
        for (int j = 0; j < n; ++j) {
            int row = list[j];
            float v = xq[(size_t)row * D + tid];
            ssum += v;
            float rq = block_sum<8>(v * v, sm);  // full-row norm, uniform across threads
            if (tid == 0) nq[row] = rq;          // row belongs to exactly one class: no race
            tsq += rq;
        }
        float nrm = block_sum<8>(ssum * ssum, sm);
        if (tid == 0) {
            qcount[c] = (float)n;
            d2sum[c] = (n > 0) ? (tsq - nrm / (float)n) : 0.f;
            if (c == 0) out[0] = 0.f;  // loss accumulator zero-init, before K2 (stream order)
        }
    }
}

// ---- K2: fused GEMM + leave-one-out logits + log-softmax + loss; block 0 also writes out[1] ----
#define ROWS 4
__global__ void loss_kernel(const float* __restrict__ xq, const int* __restrict__ ys,
                            const int* __restrict__ pos, const float* __restrict__ mus,
                            const float* __restrict__ nm, const float* __restrict__ cc,
                            const float* __restrict__ nq, const float* __restrict__ qcount,
                            const float* __restrict__ d2sum, float* __restrict__ out) {
    __shared__ __align__(16) float xqs[ROWS][D];
    __shared__ float sm[4];
    __shared__ float sh_t;
    int tid = threadIdx.x;
    int b0 = blockIdx.x * ROWS;
    for (int k = tid; k < ROWS * D; k += 256)
        xqs[k >> 9][k & (D - 1)] = xq[(size_t)b0 * D + k];
    __syncthreads();

    const float4* mrow = (const float4*)(mus + (size_t)tid * D);
    float acc[ROWS] = {0.f, 0.f, 0.f, 0.f};
    for (int d4 = 0; d4 < D / 4; ++d4) {
        float4 m = mrow[d4];
#pragma unroll
        for (int r = 0; r < ROWS; ++r) {
            const float4 xv = *(const float4*)&xqs[r][d4 * 4];
            acc[r] += m.x * xv.x + m.y * xv.y + m.z * xv.z + m.w * xv.w;
        }
    }

    float count = cc[tid];
    float nmv = nm[tid];
#pragma unroll
    for (int r = 0; r < ROWS; ++r) {
        int b = b0 + r;
        int t = ys[pos[b]];
        float nqv = nq[b];
        float g = acc[r];
        float Cn = count, dt = g, m2 = nmv;
        if (tid == t) { Cn -= 1.0f; dt = g - nqv; m2 = nmv - 2.0f * g + nqv; }
        float den = fmaxf(Cn, 0.1f);
        float inv = 1.0f / den;
        float dist2 = nqv - 2.0f * dt * inv + m2 * inv * inv;
        float logit = (Cn > 0.1f) ? (-0.5f * dist2) : 0.0f;
        if (tid == t) sh_t = logit;            // write happens-before block_max's barrier
        float mx = block_max<4>(logit, sm);
        float e = expf(logit - mx);
        float se = block_sum<4>(e, sm);
        if (tid == 0) atomicAdd(out, -(sh_t - mx - logf(se)) * (1.0f / (float)B));
        __syncthreads();  // protect sh_t before next row's write
    }

    if (blockIdx.x == 0) {  // var_intra epilogue (inputs ready since K1)
        float cntv = qcount[tid];
        bool valid = cntv >= 3.0f;  // MIN_SAMPLES
        float tot = block_sum<4>(valid ? d2sum[tid] : 0.f, sm);
        float ctot = block_sum<4>(valid ? cntv : 0.f, sm);
        if (tid == 0) out[1] = (ctot > 0.f) ? tot / fmaxf(ctot, 1.0f) : 0.0f;
    }
}

extern "C" void kernel_launch(void* const* d_in, const int* in_sizes, int n_in,
                              void* d_out, int out_size, void* d_ws, size_t ws_size,
                              hipStream_t stream) {
    const float* xq = (const float*)d_in[0];
    const int* yq = (const int*)d_in[1];
    const float* xs = (const float*)d_in[2];
    const int* ys = (const int*)d_in[3];
    const int* pos = (const int*)d_in[4];
    float* out = (float*)d_out;

    float* ws = (float*)d_ws;
    float* mus = ws;               // C*D = 131072
    float* counts = ws + 131072;   // 256
    float* nm = ws + 131328;       // 256
    float* qcount = ws + 131584;   // 256
    float* d2sum = ws + 131840;    // 256
    float* nq = ws + 132096;       // 512
    // every slot fully overwritten each launch -> no memset needed

    stats_kernel<<<2 * C, 512, 0, stream>>>(xq, yq, xs, ys, mus, counts, nm,
                                            qcount, d2sum, nq, out);
    loss_kernel<<<B / ROWS, 256, 0, stream>>>(xq, ys, pos, mus, nm, counts, nq,
                                              qcount, d2sum, out);
}

// Round 5
// 37.051 us; speedup vs baseline: 2.5997x; 1.1967x over previous
//
#include <hip/hip_runtime.h>

#define D 512
#define C 256
#define B 512
#define NS 8192

__device__ __forceinline__ float wave_sum(float v) {
#pragma unroll
    for (int off = 32; off > 0; off >>= 1) v += __shfl_xor(v, off, 64);
    return v;
}
__device__ __forceinline__ float wave_max(float v) {
#pragma unroll
    for (int off = 32; off > 0; off >>= 1) v = fmaxf(v, __shfl_xor(v, off, 64));
    return v;
}
// 512-thread block (8 waves), 2 barriers per reduction
__device__ __forceinline__ float block_sum8(float v, float* sm) {
    v = wave_sum(v);
    int tid = threadIdx.x;
    if ((tid & 63) == 0) sm[tid >> 6] = v;
    __syncthreads();
    float r = ((sm[0] + sm[1]) + (sm[2] + sm[3])) + ((sm[4] + sm[5]) + (sm[6] + sm[7]));
    __syncthreads();
    return r;
}
__device__ __forceinline__ float block_max8(float v, float* sm) {
    v = wave_max(v);
    int tid = threadIdx.x;
    if ((tid & 63) == 0) sm[tid >> 6] = v;
    __syncthreads();
    float r = fmaxf(fmaxf(fmaxf(sm[0], sm[1]), fmaxf(sm[2], sm[3])),
                    fmaxf(fmaxf(sm[4], sm[5]), fmaxf(sm[6], sm[7])));
    __syncthreads();
    return r;
}

// ---- K1: blocks [0,C) = class prototypes from xs; blocks [C,2C) = query stats + row norms ----
__global__ void stats_kernel(const float* __restrict__ xq, const int* __restrict__ yq,
                             const float* __restrict__ xs, const int* __restrict__ ys,
                             float* __restrict__ mus, float* __restrict__ counts,
                             float* __restrict__ nm, float* __restrict__ qcount,
                             float* __restrict__ d2sum, float* __restrict__ nq,
                             float* __restrict__ out) {
    __shared__ int list[NS];  // 32 KB
    __shared__ int cnt;
    __shared__ float sm[8];
    int bid = blockIdx.x, tid = threadIdx.x;

    if (bid < C) {
        int c = bid;
        if (tid == 0) cnt = 0;
        __syncthreads();
        for (int i = tid; i < NS; i += 512)
            if (ys[i] == c) { int p = atomicAdd(&cnt, 1); list[p] = i; }
        __syncthreads();
        int n = cnt;
        // 16-deep clamped gather: no serial remainder, 16 loads in flight
        float acc[16];
#pragma unroll
        for (int k = 0; k < 16; ++k) acc[k] = 0.f;
        for (int base = 0; base < n; base += 16) {
#pragma unroll
            for (int k = 0; k < 16; ++k) {
                int jj = base + k;
                int row = list[jj < n ? jj : n - 1];
                float v = xs[(size_t)row * D + tid];
                acc[k] += (jj < n) ? v : 0.f;
            }
        }
        float m = (((acc[0] + acc[1]) + (acc[2] + acc[3])) + ((acc[4] + acc[5]) + (acc[6] + acc[7]))) +
                  (((acc[8] + acc[9]) + (acc[10] + acc[11])) + ((acc[12] + acc[13]) + (acc[14] + acc[15])));
        if (n == 0) m = 0.f;
        mus[(size_t)c * D + tid] = m;
        float s = block_sum8(m * m, sm);
        if (tid == 0) { nm[c] = s; counts[c] = (float)n; }
    } else {
        int c = bid - C;
        if (tid == 0) cnt = 0;
        __syncthreads();
        if (yq[tid] == c) { int p = atomicAdd(&cnt, 1); list[p] = tid; }  // blockDim == B
        __syncthreads();
        int n = cnt;
        float ssum = 0.f, tsq = 0.f;
        for (int j = 0; j < n; ++j) {
            int row = list[j];
            float v = xq[(size_t)row * D + tid];
            ssum += v;
            float rq = block_sum8(v * v, sm);  // uniform across threads
            if (tid == 0) nq[row] = rq;        // row belongs to exactly one class
            tsq += rq;
        }
        float nrm = block_sum8(ssum * ssum, sm);
        if (tid == 0) {
            qcount[c] = (float)n;
            d2sum[c] = (n > 0) ? (tsq - nrm / (float)n) : 0.f;
            if (c == 0) out[0] = 0.f;  // loss accumulator, stream-ordered before K2
        }
    }
}

// ---- K2: 256 blocks x 512 threads, 2 rows/block, split-K over D, 8-deep load pipeline ----
__global__ void loss_kernel(const float* __restrict__ xq, const int* __restrict__ ys,
                            const int* __restrict__ pos, const float* __restrict__ mus,
                            const float* __restrict__ nm, const float* __restrict__ cc,
                            const float* __restrict__ nq, const float* __restrict__ qcount,
                            const float* __restrict__ d2sum, float* __restrict__ out) {
    __shared__ __align__(16) float xq2[2][D];   // 4 KB
    __shared__ float part[2][512];              // 4 KB
    __shared__ float sm[8];
    __shared__ float sh_t;
    int tid = threadIdx.x;
    int b0 = blockIdx.x * 2;

    for (int k = tid; k < 2 * D; k += 512)
        xq2[k >> 9][k & (D - 1)] = xq[(size_t)b0 * D + k];
    __syncthreads();

    int c = tid & (C - 1);
    int half = tid >> 8;  // split-K over two 256-dim halves
    const float4* mp = (const float4*)(mus + (size_t)c * D + half * 256);
    const float4* x0 = (const float4*)(&xq2[0][half * 256]);
    const float4* x1 = (const float4*)(&xq2[1][half * 256]);
    float a0 = 0.f, a1 = 0.f;
#pragma unroll
    for (int i0 = 0; i0 < 64; i0 += 8) {
        float4 m[8];
#pragma unroll
        for (int k = 0; k < 8; ++k) m[k] = mp[i0 + k];  // 8 L2 loads in flight
#pragma unroll
        for (int k = 0; k < 8; ++k) {
            float4 v0 = x0[i0 + k];  // LDS broadcast
            float4 v1 = x1[i0 + k];
            a0 += m[k].x * v0.x + m[k].y * v0.y + m[k].z * v0.z + m[k].w * v0.w;
            a1 += m[k].x * v1.x + m[k].y * v1.y + m[k].z * v1.z + m[k].w * v1.w;
        }
    }
    part[0][tid] = a0;
    part[1][tid] = a1;
    __syncthreads();

    float count = 0.f, nmv = 0.f;
    if (tid < C) { count = cc[tid]; nmv = nm[tid]; }

#pragma unroll
    for (int r = 0; r < 2; ++r) {
        int b = b0 + r;
        int t = ys[pos[b]];
        float nqv = nq[b];
        float logit = -1e30f;
        if (tid < C) {
            float g = part[r][tid] + part[r][tid + C];
            float Cn = count, dt = g, m2 = nmv;
            if (tid == t) { Cn -= 1.0f; dt = g - nqv; m2 = nmv - 2.0f * g + nqv; }
            float den = fmaxf(Cn, 0.1f);
            float inv = 1.0f / den;
            float dist2 = nqv - 2.0f * dt * inv + m2 * inv * inv;
            logit = (Cn > 0.1f) ? (-0.5f * dist2) : 0.0f;
            if (tid == t) sh_t = logit;  // visible after block_max8's barrier
        }
        float mx = block_max8(logit, sm);
        float e = (tid < C) ? expf(logit - mx) : 0.f;
        float se = block_sum8(e, sm);
        if (tid == 0) atomicAdd(out, -(sh_t - mx - logf(se)) * (1.0f / (float)B));
        __syncthreads();  // protect sh_t before next row's write
    }

    if (blockIdx.x == 0) {  // var_intra epilogue
        float cv = (tid < C) ? qcount[tid] : 0.f;
        float dv = (tid < C) ? d2sum[tid] : 0.f;
        bool valid = cv >= 3.0f;  // MIN_SAMPLES
        float tot = block_sum8(valid ? dv : 0.f, sm);
        float ctot = block_sum8(valid ? cv : 0.f, sm);
        if (tid == 0) out[1] = (ctot > 0.f) ? tot / fmaxf(ctot, 1.0f) : 0.0f;
    }
}

extern "C" void kernel_launch(void* const* d_in, const int* in_sizes, int n_in,
                              void* d_out, int out_size, void* d_ws, size_t ws_size,
                              hipStream_t stream) {
    const float* xq = (const float*)d_in[0];
    const int* yq = (const int*)d_in[1];
    const float* xs = (const float*)d_in[2];
    const int* ys = (const int*)d_in[3];
    const int* pos = (const int*)d_in[4];
    float* out = (float*)d_out;

    float* ws = (float*)d_ws;
    float* mus = ws;               // C*D = 131072
    float* counts = ws + 131072;   // 256
    float* nm = ws + 131328;       // 256
    float* qcount = ws + 131584;   // 256
    float* d2sum = ws + 131840;    // 256
    float* nq = ws + 132096;       // 512
    // every slot fully overwritten each launch -> no memset needed

    stats_kernel<<<2 * C, 512, 0, stream>>>(xq, yq, xs, ys, mus, counts, nm,
                                            qcount, d2sum, nq, out);
    loss_kernel<<<C, 512, 0, stream>>>(xq, ys, pos, mus, nm, counts, nq,
                                       qcount, d2sum, out);
}

// Round 6
// 26.394 us; speedup vs baseline: 3.6494x; 1.4038x over previous
//
#include <hip/hip_runtime.h>

#define D 512
#define C 256
#define B 512
#define NS 8192

__device__ __forceinline__ float wave_sum(float v) {
#pragma unroll
    for (int off = 32; off > 0; off >>= 1) v += __shfl_xor(v, off, 64);
    return v;
}
__device__ __forceinline__ float wave_max(float v) {
#pragma unroll
    for (int off = 32; off > 0; off >>= 1) v = fmaxf(v, __shfl_xor(v, off, 64));
    return v;
}
// full 512-thread (8-wave) reductions, 2 barriers
__device__ __forceinline__ float block_sum8(float v, float* sm) {
    v = wave_sum(v);
    int tid = threadIdx.x;
    if ((tid & 63) == 0) sm[tid >> 6] = v;
    __syncthreads();
    float r = ((sm[0] + sm[1]) + (sm[2] + sm[3])) + ((sm[4] + sm[5]) + (sm[6] + sm[7]));
    __syncthreads();
    return r;
}
// per-half (4-wave) reductions: threads 0-255 and 256-511 reduce independently
__device__ __forceinline__ float half_sum(float v, float* sm) {
    v = wave_sum(v);
    int tid = threadIdx.x;
    if ((tid & 63) == 0) sm[tid >> 6] = v;
    __syncthreads();
    int base = (tid >> 8) << 2;
    float r = (sm[base] + sm[base + 1]) + (sm[base + 2] + sm[base + 3]);
    __syncthreads();
    return r;
}
__device__ __forceinline__ float half_max(float v, float* sm) {
    v = wave_max(v);
    int tid = threadIdx.x;
    if ((tid & 63) == 0) sm[tid >> 6] = v;
    __syncthreads();
    int base = (tid >> 8) << 2;
    float r = fmaxf(fmaxf(sm[base], sm[base + 1]), fmaxf(sm[base + 2], sm[base + 3]));
    __syncthreads();
    return r;
}

// ---- K1: blocks [0,C) = class prototypes from xs (writes musT transposed);
//          blocks [C,2C) = query stats + per-row norms ----
__global__ void stats_kernel(const float* __restrict__ xq, const int* __restrict__ yq,
                             const float* __restrict__ xs, const int* __restrict__ ys,
                             float* __restrict__ musT, float* __restrict__ counts,
                             float* __restrict__ nm, float* __restrict__ qcount,
                             float* __restrict__ d2sum, float* __restrict__ nq,
                             float* __restrict__ out) {
    __shared__ int list[NS];  // 32 KB
    __shared__ int cnt;
    __shared__ float sm[8];
    int bid = blockIdx.x, tid = threadIdx.x;

    if (bid < C) {
        int c = bid;
        if (tid == 0) cnt = 0;
        __syncthreads();
        for (int i = tid; i < NS; i += 512)
            if (ys[i] == c) { int p = atomicAdd(&cnt, 1); list[p] = i; }
        __syncthreads();
        int n = cnt;
        float acc[16];
#pragma unroll
        for (int k = 0; k < 16; ++k) acc[k] = 0.f;
        for (int base = 0; base < n; base += 16) {
#pragma unroll
            for (int k = 0; k < 16; ++k) {
                int jj = base + k;
                int row = list[jj < n ? jj : n - 1];
                float v = xs[(size_t)row * D + tid];
                acc[k] += (jj < n) ? v : 0.f;
            }
        }
        float m = (((acc[0] + acc[1]) + (acc[2] + acc[3])) + ((acc[4] + acc[5]) + (acc[6] + acc[7]))) +
                  (((acc[8] + acc[9]) + (acc[10] + acc[11])) + ((acc[12] + acc[13]) + (acc[14] + acc[15])));
        if (n == 0) m = 0.f;
        musT[(size_t)tid * C + c] = m;  // transposed store (scattered 4B, fire-and-forget)
        float s = block_sum8(m * m, sm);
        if (tid == 0) { nm[c] = s; counts[c] = (float)n; }
    } else {
        int c = bid - C;
        if (tid == 0) cnt = 0;
        __syncthreads();
        if (yq[tid] == c) { int p = atomicAdd(&cnt, 1); list[p] = tid; }  // blockDim == B
        __syncthreads();
        int n = cnt;
        float ssum = 0.f, tsq = 0.f;
        for (int j = 0; j < n; ++j) {
            int row = list[j];
            float v = xq[(size_t)row * D + tid];
            ssum += v;
            float rq = block_sum8(v * v, sm);
            if (tid == 0) nq[row] = rq;  // row belongs to exactly one class
            tsq += rq;
        }
        float nrm = block_sum8(ssum * ssum, sm);
        if (tid == 0) {
            qcount[c] = (float)n;
            d2sum[c] = (n > 0) ? (tsq - nrm / (float)n) : 0.f;
            if (c == 0) out[0] = 0.f;  // loss accumulator, stream-ordered before K2
        }
    }
}

// ---- K2: 256 blocks x 512 threads, 2 query rows/block ----
// wave w owns dims [64w,64w+64); lane owns 4 classes (cbase=4*lane); xq in regs via readlane
__global__ void loss_kernel(const float* __restrict__ xq, const int* __restrict__ ys,
                            const int* __restrict__ pos, const float* __restrict__ musT,
                            const float* __restrict__ nm, const float* __restrict__ cc,
                            const float* __restrict__ nq, const float* __restrict__ qcount,
                            const float* __restrict__ d2sum, float* __restrict__ out) {
    __shared__ float part[2][8][C];  // 16 KB K-slice partials
    __shared__ float sm[8];
    __shared__ float sh_t[2];
    int tid = threadIdx.x;
    int b0 = blockIdx.x * 2;
    int lane = tid & 63;
    int ks = tid >> 6;            // wave id = K slice
    int dbase = ks << 6;          // 64*ks
    int cbase = lane << 2;        // 4 classes per lane

    // per-wave xq slice in registers: lane l holds xq[row][dbase+l]
    float xr0 = xq[(size_t)(b0 + 0) * D + dbase + lane];
    float xr1 = xq[(size_t)(b0 + 1) * D + dbase + lane];

    const float* mtb = musT + (size_t)dbase * C + cbase;
    float4 a0 = make_float4(0.f, 0.f, 0.f, 0.f);
    float4 a1 = make_float4(0.f, 0.f, 0.f, 0.f);
#pragma unroll
    for (int j0 = 0; j0 < 64; j0 += 8) {
        float4 m[8];
#pragma unroll
        for (int k = 0; k < 8; ++k)
            m[k] = *(const float4*)(mtb + (size_t)(j0 + k) * C);  // 1KB/wave-instr, coalesced
#pragma unroll
        for (int k = 0; k < 8; ++k) {
            float x0 = __int_as_float(__builtin_amdgcn_readlane(__float_as_int(xr0), j0 + k));
            float x1 = __int_as_float(__builtin_amdgcn_readlane(__float_as_int(xr1), j0 + k));
            a0.x += m[k].x * x0; a0.y += m[k].y * x0; a0.z += m[k].z * x0; a0.w += m[k].w * x0;
            a1.x += m[k].x * x1; a1.y += m[k].y * x1; a1.z += m[k].z * x1; a1.w += m[k].w * x1;
        }
    }
    *(float4*)&part[0][ks][cbase] = a0;
    *(float4*)&part[1][ks][cbase] = a1;
    __syncthreads();

    // threads 0-255 -> row 0, threads 256-511 -> row 1 (concurrent softmaxes)
    int h = tid >> 8;
    int c = tid & (C - 1);
    int b = b0 + h;
    float g = 0.f;
#pragma unroll
    for (int k = 0; k < 8; ++k) g += part[h][k][c];

    int t = ys[pos[b]];
    float nqv = nq[b];
    float count = cc[c], nmv = nm[c];
    float Cn = count, dt = g, m2 = nmv;
    if (c == t) { Cn -= 1.0f; dt = g - nqv; m2 = nmv - 2.0f * g + nqv; }
    float den = fmaxf(Cn, 0.1f);
    float inv = 1.0f / den;
    float dist2 = nqv - 2.0f * dt * inv + m2 * inv * inv;
    float logit = (Cn > 0.1f) ? (-0.5f * dist2) : 0.0f;
    if (c == t) sh_t[h] = logit;  // visible after half_max's barrier

    float mx = half_max(logit, sm);
    float e = expf(logit - mx);
    float se = half_sum(e, sm);
    if (c == 0) atomicAdd(out, -(sh_t[h] - mx - logf(se)) * (1.0f / (float)B));

    if (blockIdx.x == 0) {  // var_intra epilogue
        float cv = (tid < C) ? qcount[tid] : 0.f;
        float dv = (tid < C) ? d2sum[tid] : 0.f;
        bool valid = cv >= 3.0f;  // MIN_SAMPLES
        float tot = block_sum8(valid ? dv : 0.f, sm);
        float ctot = block_sum8(valid ? cv : 0.f, sm);
        if (tid == 0) out[1] = (ctot > 0.f) ? tot / fmaxf(ctot, 1.0f) : 0.0f;
    }
}

extern "C" void kernel_launch(void* const* d_in, const int* in_sizes, int n_in,
                              void* d_out, int out_size, void* d_ws, size_t ws_size,
                              hipStream_t stream) {
    const float* xq = (const float*)d_in[0];
    const int* yq = (const int*)d_in[1];
    const float* xs = (const float*)d_in[2];
    const int* ys = (const int*)d_in[3];
    const int* pos = (const int*)d_in[4];
    float* out = (float*)d_out;

    float* ws = (float*)d_ws;
    float* musT = ws;              // D*C = 131072 (transposed: musT[d][c])
    float* counts = ws + 131072;   // 256
    float* nm = ws + 131328;       // 256
    float* qcount = ws + 131584;   // 256
    float* d2sum = ws + 131840;    // 256
    float* nq = ws + 132096;       // 512
    // every slot fully overwritten each launch -> no memset needed

    stats_kernel<<<2 * C, 512, 0, stream>>>(xq, yq, xs, ys, musT, counts, nm,
                                            qcount, d2sum, nq, out);
    loss_kernel<<<C, 512, 0, stream>>>(xq, ys, pos, musT, nm, counts, nq,
                                       qcount, d2sum, out);
}

// Round 7
// 25.003 us; speedup vs baseline: 3.8524x; 1.0556x over previous
//
#include <hip/hip_runtime.h>

#define D 512
#define C 256
#define B 512
#define NS 8192

__device__ __forceinline__ float wave_sum(float v) {
#pragma unroll
    for (int off = 32; off > 0; off >>= 1) v += __shfl_xor(v, off, 64);
    return v;
}
__device__ __forceinline__ float wave_max(float v) {
#pragma unroll
    for (int off = 32; off > 0; off >>= 1) v = fmaxf(v, __shfl_xor(v, off, 64));
    return v;
}
// full 512-thread (8-wave) reduction, 2 barriers
__device__ __forceinline__ float block_sum8(float v, float* sm) {
    v = wave_sum(v);
    int tid = threadIdx.x;
    if ((tid & 63) == 0) sm[tid >> 6] = v;
    __syncthreads();
    float r = ((sm[0] + sm[1]) + (sm[2] + sm[3])) + ((sm[4] + sm[5]) + (sm[6] + sm[7]));
    __syncthreads();
    return r;
}
// per-half (4-wave) reductions: threads 0-255 / 256-511 independent
__device__ __forceinline__ float half_sum(float v, float* sm) {
    v = wave_sum(v);
    int tid = threadIdx.x;
    if ((tid & 63) == 0) sm[tid >> 6] = v;
    __syncthreads();
    int base = (tid >> 8) << 2;
    float r = (sm[base] + sm[base + 1]) + (sm[base + 2] + sm[base + 3]);
    __syncthreads();
    return r;
}
__device__ __forceinline__ float half_max(float v, float* sm) {
    v = wave_max(v);
    int tid = threadIdx.x;
    if ((tid & 63) == 0) sm[tid >> 6] = v;
    __syncthreads();
    int base = (tid >> 8) << 2;
    float r = fmaxf(fmaxf(sm[base], sm[base + 1]), fmaxf(sm[base + 2], sm[base + 3]));
    __syncthreads();
    return r;
}

// ---- K1: blocks [0,C) = class prototypes (bf16 transposed store);
//          blocks [C,2C) = query class stats ----
__global__ __launch_bounds__(512) void stats_kernel(
        const float* __restrict__ xq, const int* __restrict__ yq,
        const float* __restrict__ xs, const int* __restrict__ ys,
        unsigned short* __restrict__ musT, float* __restrict__ counts,
        float* __restrict__ nm, float* __restrict__ qcount,
        float* __restrict__ d2sum, float* __restrict__ out) {
    __shared__ unsigned short list[NS];           // 16 KB
    __shared__ int cnt;
    __shared__ float sm[8];
    __shared__ __align__(16) float part4[4][D];   // 8 KB
    int bid = blockIdx.x, tid = threadIdx.x;

    if (bid < C) {
        int c = bid;
        if (tid == 0) cnt = 0;
        __syncthreads();
        for (int i = tid; i < NS; i += 512)
            if (ys[i] == c) { int p = atomicAdd(&cnt, 1); list[p] = (unsigned short)i; }
        __syncthreads();
        int n = cnt;
        int q = tid >> 7, l = tid & 127;          // quarter-group q handles rows j%4==q
        float4 acc = make_float4(0.f, 0.f, 0.f, 0.f);
        for (int base = 0; base < n; base += 32) {
            float4 mv[8];
            float w[8];
#pragma unroll
            for (int k = 0; k < 8; ++k) {
                int jj = base + (k << 2) + q;
                int cj = jj < n ? jj : n - 1;
                int row = list[cj];
                mv[k] = *(const float4*)(xs + (size_t)row * D + (l << 2));  // 16B coalesced
                w[k] = (jj < n) ? 1.f : 0.f;
            }
#pragma unroll
            for (int k = 0; k < 8; ++k) {
                acc.x = fmaf(mv[k].x, w[k], acc.x);
                acc.y = fmaf(mv[k].y, w[k], acc.y);
                acc.z = fmaf(mv[k].z, w[k], acc.z);
                acc.w = fmaf(mv[k].w, w[k], acc.w);
            }
        }
        *(float4*)&part4[q][l << 2] = acc;
        __syncthreads();
        float m = (part4[0][tid] + part4[1][tid]) + (part4[2][tid] + part4[3][tid]);
        // bf16 RNE store, transposed
        unsigned int u = __float_as_uint(m);
        u += 0x7fffu + ((u >> 16) & 1u);
        musT[(size_t)tid * C + c] = (unsigned short)(u >> 16);
        float s = block_sum8(m * m, sm);   // nm from exact f32 prototype
        if (tid == 0) { nm[c] = s; counts[c] = (float)n; }
    } else {
        int c = bid - C;
        if (tid == 0) cnt = 0;
        __syncthreads();
        if (yq[tid] == c) { int p = atomicAdd(&cnt, 1); list[p] = (unsigned short)tid; }
        __syncthreads();
        int n = cnt;
        float ssum = 0.f, sq = 0.f;
        for (int j = 0; j < n; ++j) {
            int row = list[j];
            float v = xq[(size_t)row * D + tid];
            ssum += v;
            sq = fmaf(v, v, sq);
        }
        float nrm = block_sum8(ssum * ssum, sm);
        float tsq = block_sum8(sq, sm);
        if (tid == 0) {
            qcount[c] = (float)n;
            d2sum[c] = (n > 0) ? (tsq - nrm / (float)n) : 0.f;
            if (c == 0) out[0] = 0.f;  // loss accumulator, stream-ordered before K2
        }
    }
}

// ---- K2: 256 blocks x 512 threads, 2 query rows/block; bf16 musT, row norms computed here ----
__global__ __launch_bounds__(512) void loss_kernel(
        const float* __restrict__ xq, const int* __restrict__ ys,
        const int* __restrict__ pos, const unsigned short* __restrict__ musT,
        const float* __restrict__ nm, const float* __restrict__ cc,
        const float* __restrict__ qcount, const float* __restrict__ d2sum,
        float* __restrict__ out) {
    __shared__ float part[2][8][C];  // 16 KB K-slice partials
    __shared__ float sm[8];
    __shared__ float sh_t[2];
    int tid = threadIdx.x;
    int b0 = blockIdx.x * 2;
    int lane = tid & 63;
    int ks = tid >> 6;            // wave id = K slice
    int dbase = ks << 6;
    int cbase = lane << 2;        // 4 classes per lane

    // full rows live across the block's registers: wave ks, lane l -> dim dbase+l
    float xr0 = xq[(size_t)(b0 + 0) * D + dbase + lane];
    float xr1 = xq[(size_t)(b0 + 1) * D + dbase + lane];
    float nq0 = block_sum8(xr0 * xr0, sm);
    float nq1 = block_sum8(xr1 * xr1, sm);

    const unsigned short* mtb = musT + (size_t)dbase * C + cbase;
    float4 a0 = make_float4(0.f, 0.f, 0.f, 0.f);
    float4 a1 = make_float4(0.f, 0.f, 0.f, 0.f);
#pragma unroll
    for (int j0 = 0; j0 < 64; j0 += 8) {
        uint2 mv[8];
#pragma unroll
        for (int k = 0; k < 8; ++k)
            mv[k] = *(const uint2*)(mtb + (size_t)(j0 + k) * C);  // 512B/wave-instr, coalesced
#pragma unroll
        for (int k = 0; k < 8; ++k) {
            float x0 = __int_as_float(__builtin_amdgcn_readlane(__float_as_int(xr0), j0 + k));
            float x1 = __int_as_float(__builtin_amdgcn_readlane(__float_as_int(xr1), j0 + k));
            float c0 = __uint_as_float(mv[k].x << 16);
            float c1 = __uint_as_float(mv[k].x & 0xffff0000u);
            float c2 = __uint_as_float(mv[k].y << 16);
            float c3 = __uint_as_float(mv[k].y & 0xffff0000u);
            a0.x = fmaf(c0, x0, a0.x); a0.y = fmaf(c1, x0, a0.y);
            a0.z = fmaf(c2, x0, a0.z); a0.w = fmaf(c3, x0, a0.w);
            a1.x = fmaf(c0, x1, a1.x); a1.y = fmaf(c1, x1, a1.y);
            a1.z = fmaf(c2, x1, a1.z); a1.w = fmaf(c3, x1, a1.w);
        }
    }
    *(float4*)&part[0][ks][cbase] = a0;
    *(float4*)&part[1][ks][cbase] = a1;
    __syncthreads();

    // threads 0-255 -> row 0, threads 256-511 -> row 1 (concurrent softmaxes)
    int h = tid >> 8;
    int c = tid & (C - 1);
    int b = b0 + h;
    float g = 0.f;
#pragma unroll
    for (int k = 0; k < 8; ++k) g += part[h][k][c];

    int t = ys[pos[b]];
    float nqv = h ? nq1 : nq0;
    float count = cc[c], nmv = nm[c];
    float Cn = count, dt = g, m2 = nmv;
    if (c == t) { Cn -= 1.0f; dt = g - nqv; m2 = nmv - 2.0f * g + nqv; }
    float den = fmaxf(Cn, 0.1f);
    float inv = 1.0f / den;
    float dist2 = nqv - 2.0f * dt * inv + m2 * inv * inv;
    float logit = (Cn > 0.1f) ? (-0.5f * dist2) : 0.0f;
    if (c == t) sh_t[h] = logit;  // visible after half_max's barrier

    float mx = half_max(logit, sm);
    float e = expf(logit - mx);
    float se = half_sum(e, sm);
    if (c == 0) atomicAdd(out, -(sh_t[h] - mx - logf(se)) * (1.0f / (float)B));

    if (blockIdx.x == 0) {  // var_intra epilogue
        float cv = (tid < C) ? qcount[tid] : 0.f;
        float dv = (tid < C) ? d2sum[tid] : 0.f;
        bool valid = cv >= 3.0f;  // MIN_SAMPLES
        float tot = block_sum8(valid ? dv : 0.f, sm);
        float ctot = block_sum8(valid ? cv : 0.f, sm);
        if (tid == 0) out[1] = (ctot > 0.f) ? tot / fmaxf(ctot, 1.0f) : 0.0f;
    }
}

extern "C" void kernel_launch(void* const* d_in, const int* in_sizes, int n_in,
                              void* d_out, int out_size, void* d_ws, size_t ws_size,
                              hipStream_t stream) {
    const float* xq = (const float*)d_in[0];
    const int* yq = (const int*)d_in[1];
    const float* xs = (const float*)d_in[2];
    const int* ys = (const int*)d_in[3];
    const int* pos = (const int*)d_in[4];
    float* out = (float*)d_out;

    float* wsf = (float*)d_ws;
    unsigned short* musT = (unsigned short*)d_ws;  // D*C bf16 = 256 KB = 65536 floats
    float* counts = wsf + 65536;   // 256
    float* nm = wsf + 65792;       // 256
    float* qcount = wsf + 66048;   // 256
    float* d2sum = wsf + 66304;    // 256
    // every slot fully overwritten each launch -> no memset needed

    stats_kernel<<<2 * C, 512, 0, stream>>>(xq, yq, xs, ys, musT, counts, nm,
                                            qcount, d2sum, out);
    loss_kernel<<<C, 512, 0, stream>>>(xq, ys, pos, musT, nm, counts,
                                       qcount, d2sum, out);
}